// Round 1
// baseline (482.130 us; speedup 1.0000x reference)
//
#include <hip/hip_runtime.h>

// DirectionalProcessor: out[b,y,x,o] = bc[o] + sum_{d,c} g[b,y-dy_d,x-dx_d,c] * M_d[c,o]
// with M_d[c,o] = sum_e Wd[d,c,e] * Wc[o, d*256+e]   (Wd/Wc folded -> halves FLOPs)
// B,H,W,C = 16,64,64,256; 8 directions => implicit GEMM [65536 x 2048] @ [2048 x 256].
//
// Pipeline:
//   1) pad_convert: f32 g -> zero-padded bf16 gp[16][66][66][256] (edge handling for free)
//   2) build_mt:    Mt[d][o][c] = M_d[c,o] in bf16 (B^T layout for gemm_bt fragments)
//   3) conv_gemm:   m97-style 128x128 tile, BK=32, 16x16x32 bf16 MFMA, global_load_lds w=16

typedef unsigned short u16;
typedef unsigned int u32;
typedef __attribute__((ext_vector_type(8))) short bf16x8;   // 8 x bf16 = 4 VGPRs
typedef __attribute__((ext_vector_type(4))) float f32x4;

#define GP_BYTES 35684352    // 16*66*66*256 * 2

__device__ __forceinline__ u16 f2bf(float f) {   // RNE f32->bf16
  u32 u = __float_as_uint(f);
  u32 r = u + 0x7fffu + ((u >> 16) & 1u);
  return (u16)(r >> 16);
}

// ---------------- kernel 1: zero-padded bf16 copy of g ----------------
__global__ __launch_bounds__(256) void pad_convert(const float* __restrict__ g,
                                                   u16* __restrict__ gp) {
  int id = blockIdx.x * 256 + threadIdx.x;      // one thread per 8 channels
  if (id >= 2230272) return;                    // 16*66*66*32
  int c8 = id & 31;
  int t = id >> 5;
  int xx = t % 66;
  int s = t / 66;
  int yy = s % 66;
  int b  = s / 66;
  u32 o0 = 0, o1 = 0, o2 = 0, o3 = 0;
  if (yy != 0 && yy != 65 && xx != 0 && xx != 65) {
    const float* src = g + ((((b << 6) + yy - 1) << 6) + xx - 1) * 256 + (c8 << 3);
    float4 fa = *(const float4*)src;
    float4 fb = *(const float4*)(src + 4);
    o0 = (u32)f2bf(fa.x) | ((u32)f2bf(fa.y) << 16);
    o1 = (u32)f2bf(fa.z) | ((u32)f2bf(fa.w) << 16);
    o2 = (u32)f2bf(fb.x) | ((u32)f2bf(fb.y) << 16);
    o3 = (u32)f2bf(fb.z) | ((u32)f2bf(fb.w) << 16);
  }
  uint4 v; v.x = o0; v.y = o1; v.z = o2; v.w = o3;
  *(uint4*)(gp + (size_t)id * 8) = v;
}

// ---------------- kernel 2: Mt[d][o][c] = sum_e Wd[d][c][e]*Wc[o][d*256+e] ----------------
__global__ __launch_bounds__(256) void build_mt(const float* __restrict__ Wd,
                                                const float* __restrict__ Wc,
                                                u16* __restrict__ Mt) {
  __shared__ float sWd[32 * 65];   // [c_local][e], pad 64->65 to break 32-way bank conflict
  __shared__ float sWc[32 * 64];   // [o_local][e] (broadcast reads -> no conflict)
  int bid = blockIdx.x;            // 8 d * 8 o-tiles * 8 c-tiles = 512
  int d  = bid >> 6;
  int o0 = ((bid >> 3) & 7) << 5;
  int c0 = (bid & 7) << 5;
  int tid = threadIdx.x;
  int cl = tid & 31;               // c within tile
  int ob = (tid >> 5) << 2;        // o base within tile (4 outputs/thread)
  float a0 = 0, a1 = 0, a2 = 0, a3 = 0;
  for (int e0 = 0; e0 < 256; e0 += 64) {
    __syncthreads();
    for (int idx = tid; idx < 2048; idx += 256) {
      int r = idx >> 6, e = idx & 63;
      sWd[r * 65 + e] = Wd[(d * 256 + c0 + r) * 256 + e0 + e];
      sWc[idx]        = Wc[(o0 + r) * 2048 + d * 256 + e0 + e];
    }
    __syncthreads();
    for (int e = 0; e < 64; ++e) {
      float av = sWd[cl * 65 + e];
      a0 += av * sWc[(ob + 0) * 64 + e];
      a1 += av * sWc[(ob + 1) * 64 + e];
      a2 += av * sWc[(ob + 2) * 64 + e];
      a3 += av * sWc[(ob + 3) * 64 + e];
    }
  }
  u16* dst = Mt + (size_t)(d * 256 + o0 + ob) * 256 + c0 + cl;
  dst[0]   = f2bf(a0);
  dst[256] = f2bf(a1);
  dst[512] = f2bf(a2);
  dst[768] = f2bf(a3);
}

// ---------------- kernel 3: main implicit-GEMM conv ----------------
// directions (dx,dy) -> source offset (ox,oy)=(-dx,-dy); DOFF = (oy*66+ox)*256 in gp elems
__constant__ int DOFF[8] = {16896, 16640, -256, -17152, -16896, -16640, 256, 17152};

__device__ __forceinline__ void async16(const u16* g, u16* l) {
  __builtin_amdgcn_global_load_lds((const __attribute__((address_space(1))) u32*)g,
                                   (__attribute__((address_space(3))) u32*)l, 16, 0, 0);
}

__global__ __launch_bounds__(256) void conv_gemm(const u16* __restrict__ gp,
                                                 const u16* __restrict__ Mt,
                                                 const float* __restrict__ bc,
                                                 float* __restrict__ out) {
  __shared__ __align__(16) u16 As[128 * 32];   // 8 KB
  __shared__ __align__(16) u16 Bs[128 * 32];   // 8 KB
  const int tid = threadIdx.x;
  const int n0  = blockIdx.x << 7;             // output-channel block (0 or 128)
  const int bym = blockIdx.y;                  // 512 M-blocks of 128 positions
  const int b   = bym >> 5;
  const int y0  = (bym & 31) << 1;             // 2 image rows per M-block

  const int lane = tid & 63;
  const int wid  = tid >> 6;
  const int wm   = (wid >> 1) << 6;            // wave M offset (0/64)
  const int wn   = (wid & 1) << 6;             // wave N offset (0/64)
  const int quad = lane >> 4;
  const int r16  = lane & 15;

  // staging: thread t loads 16B for A-row (t>>2) and (t>>2)+64; LDS offset = t*16 (linear in lane)
  const int arow = tid >> 2;                   // 0..63 == x coordinate
  const int coff = (tid & 3) << 3;             // channel sub-offset
  const u16* baseA = gp + ((b * 66 + y0 + 1) * 66 + arow + 1) * 256 + coff;
  const u16* baseB = Mt + (size_t)(n0 + arow) * 256 + coff;
  u16* ldsA = As + tid * 8;
  u16* ldsB = Bs + tid * 8;

  f32x4 acc[4][4] = {};

  for (int kt = 0; kt < 64; ++kt) {            // K = 8 dirs * 256 ch, BK = 32
    const int d  = kt >> 3;
    const int c0 = (kt & 7) << 5;
    const u16* ga = baseA + DOFF[d] + c0;
    async16(ga,            ldsA);
    async16(ga + 66 * 256, ldsA + 2048);       // second image row
    const u16* gb = baseB + d * 65536 + c0;
    async16(gb,            ldsB);
    async16(gb + 64 * 256, ldsB + 2048);
    __syncthreads();                           // drains vmcnt before barrier
    bf16x8 af[4], bfr[4];
#pragma unroll
    for (int mt = 0; mt < 4; ++mt)
      af[mt] = *(const bf16x8*)&As[(wm + mt * 16 + r16) * 32 + quad * 8];
#pragma unroll
    for (int nt = 0; nt < 4; ++nt)
      bfr[nt] = *(const bf16x8*)&Bs[(wn + nt * 16 + r16) * 32 + quad * 8];
#pragma unroll
    for (int mt = 0; mt < 4; ++mt)
#pragma unroll
      for (int nt = 0; nt < 4; ++nt)
        acc[mt][nt] = __builtin_amdgcn_mfma_f32_16x16x32_bf16(af[mt], bfr[nt], acc[mt][nt], 0, 0, 0);
    __syncthreads();
  }

  // epilogue: C/D layout col=lane&15, row=quad*4+reg
  const int pbase = bym << 7;
#pragma unroll
  for (int nt = 0; nt < 4; ++nt) {
    const int o = n0 + wn + nt * 16 + r16;
    const float bias = bc[o];
#pragma unroll
    for (int mt = 0; mt < 4; ++mt) {
      const int pr = pbase + wm + mt * 16 + quad * 4;
      f32x4 v = acc[mt][nt];
#pragma unroll
      for (int r = 0; r < 4; ++r)
        out[(pr + r) * 256 + o] = v[r] + bias;
    }
  }
}

extern "C" void kernel_launch(void* const* d_in, const int* in_sizes, int n_in,
                              void* d_out, int out_size, void* d_ws, size_t ws_size,
                              hipStream_t stream) {
  const float* g  = (const float*)d_in[0];   // [16,64,64,256] f32
  const float* Wd = (const float*)d_in[1];   // [8,256,256]
  const float* Wc = (const float*)d_in[2];   // [256,2048]
  const float* bc = (const float*)d_in[3];   // [256]
  float* out = (float*)d_out;                // [16,64,64,256] f32
  u16* gp = (u16*)d_ws;                            // 35.7 MB padded bf16 input
  u16* Mt = (u16*)((char*)d_ws + GP_BYTES);        // 1 MB folded weights (B^T)

  pad_convert<<<8712, 256, 0, stream>>>(g, gp);
  build_mt<<<512, 256, 0, stream>>>(Wd, Wc, Mt);
  conv_gemm<<<dim3(2, 512), 256, 0, stream>>>(gp, Mt, bc, out);
}

// Round 2
// 233.960 us; speedup vs baseline: 2.0607x; 2.0607x over previous
//
#include <hip/hip_runtime.h>

// DirectionalProcessor: out[b,y,x,o] = bc[o] + sum_{d,c} g[b,y-dy_d,x-dx_d,c] * M_d[c,o]
// with M_d[c,o] = sum_e Wd[d,c,e] * Wc[o, d*256+e]   (Wd/Wc folded -> halves FLOPs)
// B,H,W,C = 16,64,64,256; 8 directions => implicit GEMM [65536 x 2048] @ [2048 x 256].
//
// Pipeline:
//   1) pad_convert: f32 g -> zero-padded bf16 gp[16][66][66][256] (edge handling for free)
//   2) build_mt:    Mt[d][o][c] = M_d[c,o] in bf16 (B^T layout for gemm_bt fragments)
//   3) conv_gemm:   m97-style 128x128 tile, BK=32, 16x16x32 bf16 MFMA, global_load_lds w=16
//
// R1 fix: build_mt was spilling (VGPR=256, ~575MB scratch HBM traffic, 275us, VALU 2%)
// because the compiler fully unrolled 256 FMA bodies and hoisted all ds_reads.
// -> __launch_bounds__(256,4) caps VGPR at 128; pinned unroll factors.

typedef unsigned short u16;
typedef unsigned int u32;
typedef __attribute__((ext_vector_type(8))) short bf16x8;   // 8 x bf16 = 4 VGPRs
typedef __attribute__((ext_vector_type(4))) float f32x4;

#define GP_BYTES 35684352    // 16*66*66*256 * 2

__device__ __forceinline__ u16 f2bf(float f) {   // RNE f32->bf16
  u32 u = __float_as_uint(f);
  u32 r = u + 0x7fffu + ((u >> 16) & 1u);
  return (u16)(r >> 16);
}

// ---------------- kernel 1: zero-padded bf16 copy of g ----------------
__global__ __launch_bounds__(256) void pad_convert(const float* __restrict__ g,
                                                   u16* __restrict__ gp) {
  int id = blockIdx.x * 256 + threadIdx.x;      // one thread per 8 channels
  if (id >= 2230272) return;                    // 16*66*66*32
  int c8 = id & 31;
  int t = id >> 5;
  int xx = t % 66;
  int s = t / 66;
  int yy = s % 66;
  int b  = s / 66;
  u32 o0 = 0, o1 = 0, o2 = 0, o3 = 0;
  if (yy != 0 && yy != 65 && xx != 0 && xx != 65) {
    const float* src = g + ((((b << 6) + yy - 1) << 6) + xx - 1) * 256 + (c8 << 3);
    float4 fa = *(const float4*)src;
    float4 fb = *(const float4*)(src + 4);
    o0 = (u32)f2bf(fa.x) | ((u32)f2bf(fa.y) << 16);
    o1 = (u32)f2bf(fa.z) | ((u32)f2bf(fa.w) << 16);
    o2 = (u32)f2bf(fb.x) | ((u32)f2bf(fb.y) << 16);
    o3 = (u32)f2bf(fb.z) | ((u32)f2bf(fb.w) << 16);
  }
  uint4 v; v.x = o0; v.y = o1; v.z = o2; v.w = o3;
  *(uint4*)(gp + (size_t)id * 8) = v;
}

// ---------------- kernel 2: Mt[d][o][c] = sum_e Wd[d][c][e]*Wc[o][d*256+e] ----------------
__global__ __launch_bounds__(256, 4) void build_mt(const float* __restrict__ Wd,
                                                   const float* __restrict__ Wc,
                                                   u16* __restrict__ Mt) {
  __shared__ float sWd[32 * 65];   // [c_local][e], pad 64->65 to break 32-way bank conflict
  __shared__ float sWc[32 * 64];   // [o_local][e] (broadcast reads -> no conflict)
  int bid = blockIdx.x;            // 8 d * 8 o-tiles * 8 c-tiles = 512
  int d  = bid >> 6;
  int o0 = ((bid >> 3) & 7) << 5;
  int c0 = (bid & 7) << 5;
  int tid = threadIdx.x;
  int cl = tid & 31;               // c within tile
  int ob = (tid >> 5) << 2;        // o base within tile (4 outputs/thread)
  float a0 = 0, a1 = 0, a2 = 0, a3 = 0;
#pragma unroll 1
  for (int e0 = 0; e0 < 256; e0 += 64) {
    __syncthreads();
#pragma unroll 1
    for (int idx = tid; idx < 2048; idx += 256) {
      int r = idx >> 6, e = idx & 63;
      sWd[r * 65 + e] = Wd[(d * 256 + c0 + r) * 256 + e0 + e];
      sWc[idx]        = Wc[(o0 + r) * 2048 + d * 256 + e0 + e];
    }
    __syncthreads();
#pragma unroll 4
    for (int e = 0; e < 64; ++e) {
      float av = sWd[cl * 65 + e];
      a0 += av * sWc[(ob + 0) * 64 + e];
      a1 += av * sWc[(ob + 1) * 64 + e];
      a2 += av * sWc[(ob + 2) * 64 + e];
      a3 += av * sWc[(ob + 3) * 64 + e];
    }
  }
  u16* dst = Mt + (size_t)(d * 256 + o0 + ob) * 256 + c0 + cl;
  dst[0]   = f2bf(a0);
  dst[256] = f2bf(a1);
  dst[512] = f2bf(a2);
  dst[768] = f2bf(a3);
}

// ---------------- kernel 3: main implicit-GEMM conv ----------------
// directions (dx,dy) -> source offset (ox,oy)=(-dx,-dy); DOFF = (oy*66+ox)*256 in gp elems
__constant__ int DOFF[8] = {16896, 16640, -256, -17152, -16896, -16640, 256, 17152};

__device__ __forceinline__ void async16(const u16* g, u16* l) {
  __builtin_amdgcn_global_load_lds((const __attribute__((address_space(1))) u32*)g,
                                   (__attribute__((address_space(3))) u32*)l, 16, 0, 0);
}

__global__ __launch_bounds__(256) void conv_gemm(const u16* __restrict__ gp,
                                                 const u16* __restrict__ Mt,
                                                 const float* __restrict__ bc,
                                                 float* __restrict__ out) {
  __shared__ __align__(16) u16 As[128 * 32];   // 8 KB
  __shared__ __align__(16) u16 Bs[128 * 32];   // 8 KB
  const int tid = threadIdx.x;
  const int n0  = blockIdx.x << 7;             // output-channel block (0 or 128)
  const int bym = blockIdx.y;                  // 512 M-blocks of 128 positions
  const int b   = bym >> 5;
  const int y0  = (bym & 31) << 1;             // 2 image rows per M-block

  const int lane = tid & 63;
  const int wid  = tid >> 6;
  const int wm   = (wid >> 1) << 6;            // wave M offset (0/64)
  const int wn   = (wid & 1) << 6;             // wave N offset (0/64)
  const int quad = lane >> 4;
  const int r16  = lane & 15;

  // staging: thread t loads 16B for A-row (t>>2) and (t>>2)+64; LDS offset = t*16 (linear in lane)
  const int arow = tid >> 2;                   // 0..63 == x coordinate
  const int coff = (tid & 3) << 3;             // channel sub-offset
  const u16* baseA = gp + ((b * 66 + y0 + 1) * 66 + arow + 1) * 256 + coff;
  const u16* baseB = Mt + (size_t)(n0 + arow) * 256 + coff;
  u16* ldsA = As + tid * 8;
  u16* ldsB = Bs + tid * 8;

  f32x4 acc[4][4] = {};

  for (int kt = 0; kt < 64; ++kt) {            // K = 8 dirs * 256 ch, BK = 32
    const int d  = kt >> 3;
    const int c0 = (kt & 7) << 5;
    const u16* ga = baseA + DOFF[d] + c0;
    async16(ga,            ldsA);
    async16(ga + 66 * 256, ldsA + 2048);       // second image row
    const u16* gb = baseB + d * 65536 + c0;
    async16(gb,            ldsB);
    async16(gb + 64 * 256, ldsB + 2048);
    __syncthreads();                           // drains vmcnt before barrier
    bf16x8 af[4], bfr[4];
#pragma unroll
    for (int mt = 0; mt < 4; ++mt)
      af[mt] = *(const bf16x8*)&As[(wm + mt * 16 + r16) * 32 + quad * 8];
#pragma unroll
    for (int nt = 0; nt < 4; ++nt)
      bfr[nt] = *(const bf16x8*)&Bs[(wn + nt * 16 + r16) * 32 + quad * 8];
#pragma unroll
    for (int mt = 0; mt < 4; ++mt)
#pragma unroll
      for (int nt = 0; nt < 4; ++nt)
        acc[mt][nt] = __builtin_amdgcn_mfma_f32_16x16x32_bf16(af[mt], bfr[nt], acc[mt][nt], 0, 0, 0);
    __syncthreads();
  }

  // epilogue: C/D layout col=lane&15, row=quad*4+reg
  const int pbase = bym << 7;
#pragma unroll
  for (int nt = 0; nt < 4; ++nt) {
    const int o = n0 + wn + nt * 16 + r16;
    const float bias = bc[o];
#pragma unroll
    for (int mt = 0; mt < 4; ++mt) {
      const int pr = pbase + wm + mt * 16 + quad * 4;
      f32x4 v = acc[mt][nt];
#pragma unroll
      for (int r = 0; r < 4; ++r)
        out[(pr + r) * 256 + o] = v[r] + bias;
    }
  }
}

extern "C" void kernel_launch(void* const* d_in, const int* in_sizes, int n_in,
                              void* d_out, int out_size, void* d_ws, size_t ws_size,
                              hipStream_t stream) {
  const float* g  = (const float*)d_in[0];   // [16,64,64,256] f32
  const float* Wd = (const float*)d_in[1];   // [8,256,256]
  const float* Wc = (const float*)d_in[2];   // [256,2048]
  const float* bc = (const float*)d_in[3];   // [256]
  float* out = (float*)d_out;                // [16,64,64,256] f32
  u16* gp = (u16*)d_ws;                            // 35.7 MB padded bf16 input
  u16* Mt = (u16*)((char*)d_ws + GP_BYTES);        // 1 MB folded weights (B^T)

  pad_convert<<<8712, 256, 0, stream>>>(g, gp);
  build_mt<<<512, 256, 0, stream>>>(Wd, Wc, Mt);
  conv_gemm<<<dim3(2, 512), 256, 0, stream>>>(gp, Mt, bc, out);
}